// Round 11
// baseline (360.176 us; speedup 1.0000x reference)
//
#include <hip/hip_runtime.h>

// ResLSTM: B=4096, T=512, H=32.
// R17 STRUCTURE: MFMA recurrence, one wave64 = SIXTEEN batch elements.
//   c = lane&15 (batch col), q = lane>>4 (row quad).
//   gates[128,16] = Whh_scaled[128,32] @ h[32,16]: 8 row-tiles x 2 K-halves
//   of v_mfma_f32_16x16x16_f16.
//   KEY LAYOUT FACT: C-output row pattern ((l>>4)*4+m) == B-input k pattern
//   ((l>>4)*4+m). Lane (c,q) outputs gate rows 16t+4q+m of batch c; the
//   units it derives h for (4q+m and 16+4q+m) are EXACTLY the k-slots of
//   its next-step B1/B2 fragments -> h never leaves registers. Zero LDS
//   broadcast, zero shuffles in the recurrence.
// R18 = R17 with a compile fix: __builtin_amdgcn_cvt_pkrtz returns
// __fp16-vector, not _Float16-vector; comb() now takes the native type
// and bit_casts (free). No logic change; R17 prediction stands.
// History: R7 341 (LDS-pipe floor @4w/SIMD). R11 2-batch 297. R12 dot2-f16
// 248 (absmax 9.8e-4 OK). R14 rcp-fusion 230. R15 poly REGRESSED (trans is
// cheap). R16 4-batch 219: dot2/batch FIXED at 32 -> VALU floor; MfmaUtil=0
// all session -> MFMA is the only remaining MAC-issue lever.
// Predict steady 219 -> 95-150 us; MfmaUtil>0 first time; absmax ~1e-3.

static constexpr int T_LEN = 512;
static constexpr int H = 32;

typedef _Float16 h2   __attribute__((ext_vector_type(2)));
typedef __fp16   fp2  __attribute__((ext_vector_type(2)));   // cvt_pkrtz type
typedef _Float16 v4h  __attribute__((ext_vector_type(4)));
typedef float    v4f  __attribute__((ext_vector_type(4)));

__device__ __forceinline__ v4h comb(fp2 a, fp2 b) {
    union { h2 p[2]; v4h v; } u;
    u.p[0] = __builtin_bit_cast(h2, a);
    u.p[1] = __builtin_bit_cast(h2, b);
    return u.v;
}

// D = A(4 f16) x B(4 f16) + C(4 f32), 16x16x16 f16 MFMA.
__device__ __forceinline__ v4f MF(v4h a, v4h b, v4f c) {
#if __has_builtin(__builtin_amdgcn_mfma_f32_16x16x16f16)
    return __builtin_amdgcn_mfma_f32_16x16x16f16(a, b, c, 0, 0, 0);
#else
    v4f d = c;
    asm("v_mfma_f32_16x16x16_f16 %0, %1, %2, %0" : "+v"(d) : "v"(a), "v"(b));
    return d;
#endif
}

__global__ void
__attribute__((amdgpu_flat_work_group_size(64, 64), amdgpu_waves_per_eu(1, 1)))
reslstm_kernel(const float* __restrict__ x,
               const float* __restrict__ W_ih,
               const float* __restrict__ W_hh,
               const float* __restrict__ b_ih,
               const float* __restrict__ b_hh,
               const float* __restrict__ W_fc,
               const float* __restrict__ b_fc,
               float* __restrict__ out, int B)
{
    // x chunk: [batch-col][t-in-chunk], pad 36 floats. Per-step read
    // xl[c][t]: 4 lanes (q) same addr = broadcast; c vs c+8 2-way (free).
    __shared__ float xl[16][36];

    const int lane = threadIdx.x & 63;
    const int c    = lane & 15;          // batch col (0..15)
    const int q    = lane >> 4;          // row quad  (0..3)

    const int wbase = blockIdx.x << 4;   // 16 batches per 64-thread block
    if (wbase >= B) return;
    const int bb   = wbase + c;
    const int bsrc = (bb < B) ? bb : (B - 1);

    constexpr float NL2E  = -1.4426950408889634f;   // -log2(e)
    constexpr float N2L2E = 2.0f * NL2E;

    // A fragments (constant): A1[t][m] = Whh_sc[16t + c][4q + m],
    //                         A2[t][m] = Whh_sc[16t + c][16 + 4q + m].
    // Row tiles: t=0,1 -> i rows 0..31; t=2,3 -> f; t=4,5 -> g (scale 2x);
    // t=6,7 -> o. Prescale by -log2(e) folds sigmoid/tanh exp2 scaling.
    // xproj consts (C-layout indexed!): wih[t][m], bsb[t][m] for row
    // 16t + 4q + m.
    v4h A1[8], A2[8];
    v4f wih[8], bsb[8];
    #pragma unroll
    for (int t = 0; t < 8; ++t) {
        const float sc = (t == 4 || t == 5) ? N2L2E : NL2E;
        const float4 w1 = *reinterpret_cast<const float4*>(
            W_hh + (16 * t + c) * H + 4 * q);
        const float4 w2 = *reinterpret_cast<const float4*>(
            W_hh + (16 * t + c) * H + 16 + 4 * q);
        A1[t][0] = (_Float16)(w1.x * sc); A1[t][1] = (_Float16)(w1.y * sc);
        A1[t][2] = (_Float16)(w1.z * sc); A1[t][3] = (_Float16)(w1.w * sc);
        A2[t][0] = (_Float16)(w2.x * sc); A2[t][1] = (_Float16)(w2.y * sc);
        A2[t][2] = (_Float16)(w2.z * sc); A2[t][3] = (_Float16)(w2.w * sc);
        const int r0 = 16 * t + 4 * q;
        const float4 wi = *reinterpret_cast<const float4*>(W_ih + r0);
        const float4 bi = *reinterpret_cast<const float4*>(b_ih + r0);
        const float4 bh = *reinterpret_cast<const float4*>(b_hh + r0);
        wih[t][0] = wi.x * sc; wih[t][1] = wi.y * sc;
        wih[t][2] = wi.z * sc; wih[t][3] = wi.w * sc;
        bsb[t][0] = (bi.x + bh.x) * sc; bsb[t][1] = (bi.y + bh.y) * sc;
        bsb[t][2] = (bi.z + bh.z) * sc; bsb[t][3] = (bi.w + bh.w) * sc;
    }

    // State. h lives ONLY in the B fragments (f16) + hv f32 mirrors.
    v4h Bf1 = comb(__builtin_amdgcn_cvt_pkrtz(0.f, 0.f),
                   __builtin_amdgcn_cvt_pkrtz(0.f, 0.f));
    v4h Bf2 = Bf1;
    float c00 = 0.f, c01 = 0.f, c02 = 0.f, c03 = 0.f;
    float c10 = 0.f, c11 = 0.f, c12 = 0.f, c13 = 0.f;
    float hv00 = 0.f, hv01 = 0.f, hv02 = 0.f, hv03 = 0.f;
    float hv10 = 0.f, hv11 = 0.f, hv12 = 0.f, hv13 = 0.f;

    const float* xrow = x + (size_t)bsrc * T_LEN;

// Light pins once per chunk (R13: placement neutral; R6 lesson: asm outputs
// cannot be rematerialized from memory -> weights stay VGPR-resident).
#define PINALL()                                                              \
    asm volatile("" : "+v"(A1[0]), "+v"(A1[1]), "+v"(A1[2]), "+v"(A1[3]),     \
                      "+v"(A1[4]), "+v"(A1[5]), "+v"(A1[6]), "+v"(A1[7]),     \
                      "+v"(A2[0]), "+v"(A2[1]), "+v"(A2[2]), "+v"(A2[3]),     \
                      "+v"(A2[4]), "+v"(A2[5]), "+v"(A2[6]), "+v"(A2[7]));    \
    asm volatile("" : "+v"(wih[0]), "+v"(wih[1]), "+v"(wih[2]), "+v"(wih[3]), \
                      "+v"(wih[4]), "+v"(wih[5]), "+v"(wih[6]), "+v"(wih[7]), \
                      "+v"(bsb[0]), "+v"(bsb[1]), "+v"(bsb[2]), "+v"(bsb[3]), \
                      "+v"(bsb[4]), "+v"(bsb[5]), "+v"(bsb[6]), "+v"(bsb[7]))

// R14 exp2 gate math (accums prescaled by -log2(e)):
//   c' = [c*Di*Dg + (1-Eg)*Df] * rcp(Df*Di*Dg);  h = (1-Ec) * rcp(Do*Dc).
#define GSTATE(AI, AF, AG, AO, CC, HH) do {                                   \
    const float Ei = __builtin_amdgcn_exp2f(AI);                              \
    const float Ef = __builtin_amdgcn_exp2f(AF);                              \
    const float Eg = __builtin_amdgcn_exp2f(AG);                              \
    const float Eo = __builtin_amdgcn_exp2f(AO);                              \
    const float Di = 1.0f + Ei, Df = 1.0f + Ef;                               \
    const float Dg = 1.0f + Eg, Do_ = 1.0f + Eo;                              \
    const float P  = Di * Dg;                                                 \
    const float t_ = (1.0f - Eg) * Df;                                        \
    const float u_ = __builtin_fmaf(CC, P, t_);                               \
    const float Rc = __builtin_amdgcn_rcpf(Df * P);                           \
    CC = u_ * Rc;                                                             \
    const float Ec = __builtin_amdgcn_exp2f(CC * N2L2E);                      \
    const float Dc = 1.0f + Ec;                                               \
    const float Rh = __builtin_amdgcn_rcpf(Do_ * Dc);                         \
    HH = (1.0f - Ec) * Rh;                                                    \
} while (0)

// One time step for 16 batches. acc[t][m] = gate preact row 16t+4q+m, col c.
#define STEP(XT) do {                                                         \
    const float xt = (XT);                                                    \
    v4f acc[8];                                                               \
    _Pragma("unroll")                                                         \
    for (int t = 0; t < 8; ++t) acc[t] = bsb[t] + wih[t] * xt;                \
    _Pragma("unroll")                                                         \
    for (int t = 0; t < 8; ++t) {                                             \
        acc[t] = MF(A1[t], Bf1, acc[t]);                                      \
        acc[t] = MF(A2[t], Bf2, acc[t]);                                      \
    }                                                                         \
    GSTATE(acc[0][0], acc[2][0], acc[4][0], acc[6][0], c00, hv00);            \
    GSTATE(acc[0][1], acc[2][1], acc[4][1], acc[6][1], c01, hv01);            \
    GSTATE(acc[0][2], acc[2][2], acc[4][2], acc[6][2], c02, hv02);            \
    GSTATE(acc[0][3], acc[2][3], acc[4][3], acc[6][3], c03, hv03);            \
    GSTATE(acc[1][0], acc[3][0], acc[5][0], acc[7][0], c10, hv10);            \
    GSTATE(acc[1][1], acc[3][1], acc[5][1], acc[7][1], c11, hv11);            \
    GSTATE(acc[1][2], acc[3][2], acc[5][2], acc[7][2], c12, hv12);            \
    GSTATE(acc[1][3], acc[3][3], acc[5][3], acc[7][3], c13, hv13);            \
    Bf1 = comb(__builtin_amdgcn_cvt_pkrtz(hv00, hv01),                        \
               __builtin_amdgcn_cvt_pkrtz(hv02, hv03));                       \
    Bf2 = comb(__builtin_amdgcn_cvt_pkrtz(hv10, hv11),                        \
               __builtin_amdgcn_cvt_pkrtz(hv12, hv13));                       \
} while (0)

    // Prefetch chunk 0: lane (c,q) owns x[bb][q*8 .. q*8+7].
    float4 xA = *reinterpret_cast<const float4*>(xrow + (q << 3));
    float4 xB = *reinterpret_cast<const float4*>(xrow + (q << 3) + 4);

    for (int tc = 0; tc < T_LEN / 32; ++tc) {
        PINALL();
        // Stage 32 steps of x for all 16 batches (wave-private, in-order
        // LDS pipe -> no barrier needed).
        *reinterpret_cast<float4*>(&xl[c][(q << 3)])     = xA;
        *reinterpret_cast<float4*>(&xl[c][(q << 3) + 4]) = xB;
        if (tc + 1 < T_LEN / 32) {
            xA = *reinterpret_cast<const float4*>(
                     xrow + (tc + 1) * 32 + (q << 3));
            xB = *reinterpret_cast<const float4*>(
                     xrow + (tc + 1) * 32 + (q << 3) + 4);
        }
        const float* xc = &xl[c][0];
        #pragma unroll 4
        for (int tt = 0; tt < 32; ++tt) {
            STEP(xc[tt]);
        }
    }
#undef STEP
#undef GSTATE
#undef PINALL

    // out[bb] = sum_j h[j]*W_fc[j] + b_fc.
    // Lane (c,q) holds h of units 4q+m (hv0m) and 16+4q+m (hv1m).
    const int j0 = q << 2;
    float val = hv00 * W_fc[j0]     + hv01 * W_fc[j0 + 1]
              + hv02 * W_fc[j0 + 2] + hv03 * W_fc[j0 + 3]
              + hv10 * W_fc[16 + j0]     + hv11 * W_fc[16 + j0 + 1]
              + hv12 * W_fc[16 + j0 + 2] + hv13 * W_fc[16 + j0 + 3];
    val += __shfl_xor(val, 16);
    val += __shfl_xor(val, 32);
    if (q == 0 && bb < B) out[bb] = val + b_fc[0];
}

extern "C" void kernel_launch(void* const* d_in, const int* in_sizes, int n_in,
                              void* d_out, int out_size, void* d_ws, size_t ws_size,
                              hipStream_t stream) {
    const float* x    = (const float*)d_in[0];
    const float* W_ih = (const float*)d_in[1];
    const float* W_hh = (const float*)d_in[2];
    const float* b_ih = (const float*)d_in[3];
    const float* b_hh = (const float*)d_in[4];
    const float* W_fc = (const float*)d_in[5];
    const float* b_fc = (const float*)d_in[6];
    float* out = (float*)d_out;
    const int B = in_sizes[0] / T_LEN;        // 4096
    dim3 block(64);                           // 1 wave = 16 batch elements
    dim3 grid((B + 15) / 16);                 // 256 blocks -> 1 wave/CU-SIMD
    reslstm_kernel<<<grid, block, 0, stream>>>(x, W_ih, W_hh, b_ih, b_hh,
                                               W_fc, b_fc, out, B);
}

// Round 12
// 336.265 us; speedup vs baseline: 1.0711x; 1.0711x over previous
//
#include <hip/hip_runtime.h>

// ResLSTM: B=4096, T=512, H=32.
// R19 STRUCTURE: MFMA recurrence, one wave64 = SIXTEEN batch elements,
//   now with v_mfma_f32_16x16x32_f16 (K=32): 8 MFMA/step (was 16 K=16).
//   c = lane&15 (batch col), q = lane>>4 (row quad).
//   gates[128,16] = Whh_scaled[128,32] @ h[32,16]: 8 row-tiles, one K=32
//   MFMA each. Fragment k-mapping = TWO CONCATENATED K=16 HALVES
//   (elems 0-3: k=4q+m; elems 4-7: k=16+4q+m) -- evidence: the
//   ds_read_b64_tr_b16 pattern (m156) delivers exactly this quad layout.
//   So B8 = [Bf1 || Bf2] from R18 and the C-row <-> B-k correspondence is
//   unchanged: h never leaves registers.
// R18 POST-MORTEM: absmax 9.8e-4 == R12/R14 -> LAYOUT CORRECT. 305 us =
//   1430 cy/step; only 1 of 4 SIMDs occupied -> VALUBusy 20.3% CU = ~81%
//   SIMD: ISSUE/ACTIVE-bound. Busy ~1160 cy/step vs ~340 cy hand-counted
//   VALU -> gap ~800 cy = MFMA active time (v_mfma is VALU-class, blocks
//   its wave) + VALU<->MFMA hazards. KEY: total time = ONE wave's serial
//   wall (waves independent, all co-resident) -> only shortening the
//   per-step wall helps. R19 halves MFMA count + transitions.
// History: R7 341. R11 2-batch 297. R12 dot2-f16 248. R14 rcp-fusion 230.
//   R15 poly regressed (trans cheap). R16 4-batch 219 (VALU-dot2 floor).
//   R18 MFMA K=16 305 (structure right, MFMA-active cost).
// Predict: absmax ~1e-3 (pass); dur 305 -> 230-270; MfmaUtil HALVES to
//   ~2.2% (the clean test); VALUBusy(CU) -> ~17%. Neutral dur + halved
//   MfmaUtil => MFMA-active not on wall => R20: 2-wave split w/ LDS h-swap.

static constexpr int T_LEN = 512;
static constexpr int H = 32;

typedef _Float16 h2   __attribute__((ext_vector_type(2)));
typedef __fp16   fp2  __attribute__((ext_vector_type(2)));   // cvt_pkrtz type
typedef _Float16 v4h  __attribute__((ext_vector_type(4)));
typedef _Float16 v8h  __attribute__((ext_vector_type(8)));
typedef float    v4f  __attribute__((ext_vector_type(4)));

__device__ __forceinline__ v8h comb8(fp2 a, fp2 b, fp2 cc, fp2 d) {
    union { h2 p[4]; v8h v; } u;
    u.p[0] = __builtin_bit_cast(h2, a);
    u.p[1] = __builtin_bit_cast(h2, b);
    u.p[2] = __builtin_bit_cast(h2, cc);
    u.p[3] = __builtin_bit_cast(h2, d);
    return u.v;
}

// D = A(8 f16) x B(8 f16) + C(4 f32), 16x16x32 f16 MFMA (K=32).
__device__ __forceinline__ v4f MF32(v8h a, v8h b, v4f c) {
#if __has_builtin(__builtin_amdgcn_mfma_f32_16x16x32_f16)
    return __builtin_amdgcn_mfma_f32_16x16x32_f16(a, b, c, 0, 0, 0);
#else
    v4f d = c;
    asm("v_mfma_f32_16x16x32_f16 %0, %1, %2, %0" : "+v"(d) : "v"(a), "v"(b));
    return d;
#endif
}

__global__ void
__attribute__((amdgpu_flat_work_group_size(64, 64), amdgpu_waves_per_eu(1, 1)))
reslstm_kernel(const float* __restrict__ x,
               const float* __restrict__ W_ih,
               const float* __restrict__ W_hh,
               const float* __restrict__ b_ih,
               const float* __restrict__ b_hh,
               const float* __restrict__ W_fc,
               const float* __restrict__ b_fc,
               float* __restrict__ out, int B)
{
    // x chunk: [batch-col][t-in-chunk], pad 36 floats. Per-step read
    // xl[c][t]: 4 lanes (q) same addr = broadcast; c vs c+8 2-way (free).
    __shared__ float xl[16][36];

    const int lane = threadIdx.x & 63;
    const int c    = lane & 15;          // batch col (0..15)
    const int q    = lane >> 4;          // row quad  (0..3)

    const int wbase = blockIdx.x << 4;   // 16 batches per 64-thread block
    if (wbase >= B) return;
    const int bb   = wbase + c;
    const int bsrc = (bb < B) ? bb : (B - 1);

    constexpr float NL2E  = -1.4426950408889634f;   // -log2(e)
    constexpr float N2L2E = 2.0f * NL2E;

    // A fragments (constant), K=32 two-half layout:
    //   A8[t][m]   = Whh_sc[16t + c][4q + m]        (k-half 0)
    //   A8[t][4+m] = Whh_sc[16t + c][16 + 4q + m]   (k-half 1)
    // Row tiles: t=0,1 -> i rows 0..31; t=2,3 -> f; t=4,5 -> g (scale 2x);
    // t=6,7 -> o. Prescale by -log2(e) folds sigmoid/tanh exp2 scaling.
    // xproj consts (C-layout indexed): wih[t][m], bsb[t][m] for row 16t+4q+m.
    v8h A8[8];
    v4f wih[8], bsb[8];
    #pragma unroll
    for (int t = 0; t < 8; ++t) {
        const float sc = (t == 4 || t == 5) ? N2L2E : NL2E;
        const float4 w1 = *reinterpret_cast<const float4*>(
            W_hh + (16 * t + c) * H + 4 * q);
        const float4 w2 = *reinterpret_cast<const float4*>(
            W_hh + (16 * t + c) * H + 16 + 4 * q);
        A8[t][0] = (_Float16)(w1.x * sc); A8[t][1] = (_Float16)(w1.y * sc);
        A8[t][2] = (_Float16)(w1.z * sc); A8[t][3] = (_Float16)(w1.w * sc);
        A8[t][4] = (_Float16)(w2.x * sc); A8[t][5] = (_Float16)(w2.y * sc);
        A8[t][6] = (_Float16)(w2.z * sc); A8[t][7] = (_Float16)(w2.w * sc);
        const int r0 = 16 * t + 4 * q;
        const float4 wi = *reinterpret_cast<const float4*>(W_ih + r0);
        const float4 bi = *reinterpret_cast<const float4*>(b_ih + r0);
        const float4 bh = *reinterpret_cast<const float4*>(b_hh + r0);
        wih[t][0] = wi.x * sc; wih[t][1] = wi.y * sc;
        wih[t][2] = wi.z * sc; wih[t][3] = wi.w * sc;
        bsb[t][0] = (bi.x + bh.x) * sc; bsb[t][1] = (bi.y + bh.y) * sc;
        bsb[t][2] = (bi.z + bh.z) * sc; bsb[t][3] = (bi.w + bh.w) * sc;
    }

    // State. h lives ONLY in the B8 fragment (f16) + hv f32 mirrors.
    v8h B8 = comb8(__builtin_amdgcn_cvt_pkrtz(0.f, 0.f),
                   __builtin_amdgcn_cvt_pkrtz(0.f, 0.f),
                   __builtin_amdgcn_cvt_pkrtz(0.f, 0.f),
                   __builtin_amdgcn_cvt_pkrtz(0.f, 0.f));
    float c00 = 0.f, c01 = 0.f, c02 = 0.f, c03 = 0.f;
    float c10 = 0.f, c11 = 0.f, c12 = 0.f, c13 = 0.f;
    float hv00 = 0.f, hv01 = 0.f, hv02 = 0.f, hv03 = 0.f;
    float hv10 = 0.f, hv11 = 0.f, hv12 = 0.f, hv13 = 0.f;

    const float* xrow = x + (size_t)bsrc * T_LEN;

// Light pins once per chunk (R13: placement neutral; R6 lesson: asm outputs
// cannot be rematerialized from memory -> weights stay VGPR-resident).
#define PINALL()                                                              \
    asm volatile("" : "+v"(A8[0]), "+v"(A8[1]), "+v"(A8[2]), "+v"(A8[3]),     \
                      "+v"(A8[4]), "+v"(A8[5]), "+v"(A8[6]), "+v"(A8[7]));    \
    asm volatile("" : "+v"(wih[0]), "+v"(wih[1]), "+v"(wih[2]), "+v"(wih[3]), \
                      "+v"(wih[4]), "+v"(wih[5]), "+v"(wih[6]), "+v"(wih[7]), \
                      "+v"(bsb[0]), "+v"(bsb[1]), "+v"(bsb[2]), "+v"(bsb[3]), \
                      "+v"(bsb[4]), "+v"(bsb[5]), "+v"(bsb[6]), "+v"(bsb[7]))

// R14 exp2 gate math (accums prescaled by -log2(e)):
//   c' = [c*Di*Dg + (1-Eg)*Df] * rcp(Df*Di*Dg);  h = (1-Ec) * rcp(Do*Dc).
#define GSTATE(AI, AF, AG, AO, CC, HH) do {                                   \
    const float Ei = __builtin_amdgcn_exp2f(AI);                              \
    const float Ef = __builtin_amdgcn_exp2f(AF);                              \
    const float Eg = __builtin_amdgcn_exp2f(AG);                              \
    const float Eo = __builtin_amdgcn_exp2f(AO);                              \
    const float Di = 1.0f + Ei, Df = 1.0f + Ef;                               \
    const float Dg = 1.0f + Eg, Do_ = 1.0f + Eo;                              \
    const float P  = Di * Dg;                                                 \
    const float t_ = (1.0f - Eg) * Df;                                        \
    const float u_ = __builtin_fmaf(CC, P, t_);                               \
    const float Rc = __builtin_amdgcn_rcpf(Df * P);                           \
    CC = u_ * Rc;                                                             \
    const float Ec = __builtin_amdgcn_exp2f(CC * N2L2E);                      \
    const float Dc = 1.0f + Ec;                                               \
    const float Rh = __builtin_amdgcn_rcpf(Do_ * Dc);                         \
    HH = (1.0f - Ec) * Rh;                                                    \
} while (0)

// One time step for 16 batches. acc[t][m] = gate preact row 16t+4q+m, col c.
// 8 K=32 MFMAs, clustered back-to-back (2 VALU<->MFMA transitions/step).
#define STEP(XT) do {                                                         \
    const float xt = (XT);                                                    \
    v4f acc[8];                                                               \
    _Pragma("unroll")                                                         \
    for (int t = 0; t < 8; ++t) acc[t] = bsb[t] + wih[t] * xt;                \
    _Pragma("unroll")                                                         \
    for (int t = 0; t < 8; ++t) acc[t] = MF32(A8[t], B8, acc[t]);             \
    GSTATE(acc[0][0], acc[2][0], acc[4][0], acc[6][0], c00, hv00);            \
    GSTATE(acc[0][1], acc[2][1], acc[4][1], acc[6][1], c01, hv01);            \
    GSTATE(acc[0][2], acc[2][2], acc[4][2], acc[6][2], c02, hv02);            \
    GSTATE(acc[0][3], acc[2][3], acc[4][3], acc[6][3], c03, hv03);            \
    GSTATE(acc[1][0], acc[3][0], acc[5][0], acc[7][0], c10, hv10);            \
    GSTATE(acc[1][1], acc[3][1], acc[5][1], acc[7][1], c11, hv11);            \
    GSTATE(acc[1][2], acc[3][2], acc[5][2], acc[7][2], c12, hv12);            \
    GSTATE(acc[1][3], acc[3][3], acc[5][3], acc[7][3], c13, hv13);            \
    B8 = comb8(__builtin_amdgcn_cvt_pkrtz(hv00, hv01),                        \
               __builtin_amdgcn_cvt_pkrtz(hv02, hv03),                        \
               __builtin_amdgcn_cvt_pkrtz(hv10, hv11),                        \
               __builtin_amdgcn_cvt_pkrtz(hv12, hv13));                       \
} while (0)

    // Prefetch chunk 0: lane (c,q) owns x[bb][q*8 .. q*8+7].
    float4 xA = *reinterpret_cast<const float4*>(xrow + (q << 3));
    float4 xB = *reinterpret_cast<const float4*>(xrow + (q << 3) + 4);

    for (int tc = 0; tc < T_LEN / 32; ++tc) {
        PINALL();
        // Stage 32 steps of x for all 16 batches (wave-private, in-order
        // LDS pipe -> no barrier needed).
        *reinterpret_cast<float4*>(&xl[c][(q << 3)])     = xA;
        *reinterpret_cast<float4*>(&xl[c][(q << 3) + 4]) = xB;
        if (tc + 1 < T_LEN / 32) {
            xA = *reinterpret_cast<const float4*>(
                     xrow + (tc + 1) * 32 + (q << 3));
            xB = *reinterpret_cast<const float4*>(
                     xrow + (tc + 1) * 32 + (q << 3) + 4);
        }
        const float* xc = &xl[c][0];
        #pragma unroll 4
        for (int tt = 0; tt < 32; ++tt) {
            STEP(xc[tt]);
        }
    }
#undef STEP
#undef GSTATE
#undef PINALL

    // out[bb] = sum_j h[j]*W_fc[j] + b_fc.
    // Lane (c,q) holds h of units 4q+m (hv0m) and 16+4q+m (hv1m).
    const int j0 = q << 2;
    float val = hv00 * W_fc[j0]     + hv01 * W_fc[j0 + 1]
              + hv02 * W_fc[j0 + 2] + hv03 * W_fc[j0 + 3]
              + hv10 * W_fc[16 + j0]     + hv11 * W_fc[16 + j0 + 1]
              + hv12 * W_fc[16 + j0 + 2] + hv13 * W_fc[16 + j0 + 3];
    val += __shfl_xor(val, 16);
    val += __shfl_xor(val, 32);
    if (q == 0 && bb < B) out[bb] = val + b_fc[0];
}

extern "C" void kernel_launch(void* const* d_in, const int* in_sizes, int n_in,
                              void* d_out, int out_size, void* d_ws, size_t ws_size,
                              hipStream_t stream) {
    const float* x    = (const float*)d_in[0];
    const float* W_ih = (const float*)d_in[1];
    const float* W_hh = (const float*)d_in[2];
    const float* b_ih = (const float*)d_in[3];
    const float* b_hh = (const float*)d_in[4];
    const float* W_fc = (const float*)d_in[5];
    const float* b_fc = (const float*)d_in[6];
    float* out = (float*)d_out;
    const int B = in_sizes[0] / T_LEN;        // 4096
    dim3 block(64);                           // 1 wave = 16 batch elements
    dim3 grid((B + 15) / 16);                 // 256 blocks -> 1 wave/CU
    reslstm_kernel<<<grid, block, 0, stream>>>(x, W_ih, W_hh, b_ih, b_hh,
                                               W_fc, b_fc, out, B);
}

// Round 13
// 249.994 us; speedup vs baseline: 1.4407x; 1.3451x over previous
//
#include <hip/hip_runtime.h>

// ResLSTM: B=4096, T=512, H=32.
// R20 STRUCTURE: MFMA recurrence, TWO COOPERATING WAVES per 16 batches.
//   Block = 128 threads = 2 waves; wave w computes tiles t in {w,w+2,w+4,w+6}
//   (= gate rows of units 16w..16w+15): 4 MFMA K=32 + 4 GSTATE per wave.
//   B-fragment halves == unit halves (elems 0-3: k=4q+m -> units 0..15;
//   elems 4-7: k=16+4q+m -> units 16..31), so per-step exchange is one
//   ds_write_b64 + barrier + ds_read_b128, DOUBLE-BUFFERED by step parity
//   (single barrier/step; write(t+1) to other buffer, ordered after
//   read(t-2) by barrier(t-1) -> race-free).
// R19 POST-MORTEM: MfmaUtil exactly halved (4.43->2.43), absmax identical
//   -> K=32 layout right. Wall only 1430->1310 cy/step: K=32 has 2x FLOPs
//   per instr on the same pipe, so ~600 cy MFMA-active remains; only
//   transition overhead saved. Step = 600 MFMA + ~480 VALU + ~230 ovh,
//   SERIAL in one wave, 3/4 SIMDs idle. R20 halves the serial wall by
//   splitting across 2 waves (512 waves -> 2 SIMDs/CU).
// History: R7 341. R11 297. R12 dot2 248. R14 230. R15 poly regressed.
//   R16 4-batch VALU floor 219. R18 MFMA K=16 305. R19 K=32 279.
// Predict: 279 -> 150-190 us; MfmaUtil ~4.5-5%; VALUBusy(CU) ~35-42%;
//   absmax EXACTLY 0.0009765625 (same tiles, same GSTATE inputs).
//   Failure >=230: exchange latency dominates -> skew waves or near-floor.

static constexpr int T_LEN = 512;
static constexpr int H = 32;

typedef _Float16 h2   __attribute__((ext_vector_type(2)));
typedef __fp16   fp2  __attribute__((ext_vector_type(2)));   // cvt_pkrtz type
typedef _Float16 v8h  __attribute__((ext_vector_type(8)));
typedef float    v4f  __attribute__((ext_vector_type(4)));

// D = A(8 f16) x B(8 f16) + C(4 f32), 16x16x32 f16 MFMA (K=32).
__device__ __forceinline__ v4f MF32(v8h a, v8h b, v4f c) {
#if __has_builtin(__builtin_amdgcn_mfma_f32_16x16x32_f16)
    return __builtin_amdgcn_mfma_f32_16x16x32_f16(a, b, c, 0, 0, 0);
#else
    v4f d = c;
    asm("v_mfma_f32_16x16x32_f16 %0, %1, %2, %0" : "+v"(d) : "v"(a), "v"(b));
    return d;
#endif
}

__device__ __forceinline__ v8h mkB(uint4 w) {
    union { uint4 u; v8h v; } u;
    u.u = w; return u.v;
}

__global__ void
__attribute__((amdgpu_flat_work_group_size(128, 128), amdgpu_waves_per_eu(1, 1)))
reslstm_kernel(const float* __restrict__ x,
               const float* __restrict__ W_ih,
               const float* __restrict__ W_hh,
               const float* __restrict__ b_ih,
               const float* __restrict__ b_hh,
               const float* __restrict__ W_fc,
               const float* __restrict__ b_fc,
               float* __restrict__ out, int B)
{
    // x chunk: [batch-col][t], pad 36.
    __shared__ float xl[16][36];
    // h exchange, double-buffered by step parity: [buf][q][c][wave] 8B slots.
    // Read as uint4 at [buf][q][c][0] -> both halves (units 0-15 | 16-31).
    __shared__ uint2 hx[2][4][16][2];
    __shared__ float osum[2][16];

    const int tid  = threadIdx.x;
    const int lane = tid & 63;
    const int wv   = tid >> 6;           // wave 0: units 0-15, wave 1: 16-31
    const int c    = lane & 15;          // batch col (0..15)
    const int q    = lane >> 4;          // row quad  (0..3)

    const int wbase = blockIdx.x << 4;   // 16 batches per block
    if (wbase >= B) return;              // block-uniform guard
    const int bb = wbase + c;

    constexpr float NL2E  = -1.4426950408889634f;   // -log2(e)
    constexpr float N2L2E = 2.0f * NL2E;

    // A fragments: tile t = 2k + wv (gate k of unit-half wv).
    //   A8[k][m]   = Whh_sc[16t + c][4q + m]      (k-half 0)
    //   A8[k][4+m] = Whh_sc[16t + c][16 + 4q + m] (k-half 1)
    // Prescale: g gate (k==2) by 2*-log2(e), else -log2(e).
    // xproj consts indexed by C layout: row 16t + 4q + m.
    v8h A8[4];
    v4f wih[4], bsb[4];
    #pragma unroll
    for (int k = 0; k < 4; ++k) {
        const int   t  = 2 * k + wv;
        const float sc = (k == 2) ? N2L2E : NL2E;
        const float4 w1 = *reinterpret_cast<const float4*>(
            W_hh + (16 * t + c) * H + 4 * q);
        const float4 w2 = *reinterpret_cast<const float4*>(
            W_hh + (16 * t + c) * H + 16 + 4 * q);
        A8[k][0] = (_Float16)(w1.x * sc); A8[k][1] = (_Float16)(w1.y * sc);
        A8[k][2] = (_Float16)(w1.z * sc); A8[k][3] = (_Float16)(w1.w * sc);
        A8[k][4] = (_Float16)(w2.x * sc); A8[k][5] = (_Float16)(w2.y * sc);
        A8[k][6] = (_Float16)(w2.z * sc); A8[k][7] = (_Float16)(w2.w * sc);
        const int r0 = 16 * t + 4 * q;
        const float4 wi = *reinterpret_cast<const float4*>(W_ih + r0);
        const float4 bi = *reinterpret_cast<const float4*>(b_ih + r0);
        const float4 bh = *reinterpret_cast<const float4*>(b_hh + r0);
        wih[k][0] = wi.x * sc; wih[k][1] = wi.y * sc;
        wih[k][2] = wi.z * sc; wih[k][3] = wi.w * sc;
        bsb[k][0] = (bi.x + bh.x) * sc; bsb[k][1] = (bi.y + bh.y) * sc;
        bsb[k][2] = (bi.z + bh.z) * sc; bsb[k][3] = (bi.w + bh.w) * sc;
    }

    // State: this wave's 4 units (16wv + 4q + m).
    float cs0 = 0.f, cs1 = 0.f, cs2 = 0.f, cs3 = 0.f;
    float hv0 = 0.f, hv1 = 0.f, hv2 = 0.f, hv3 = 0.f;
    v8h B8 = mkB(uint4{0u, 0u, 0u, 0u});          // h(0) = 0

// Light pins once per chunk (R6 lesson: asm outputs can't be rematerialized
// from memory -> weights stay VGPR-resident; R13: placement neutral).
#define PINALL()                                                              \
    asm volatile("" : "+v"(A8[0]), "+v"(A8[1]), "+v"(A8[2]), "+v"(A8[3]));    \
    asm volatile("" : "+v"(wih[0]), "+v"(wih[1]), "+v"(wih[2]), "+v"(wih[3]), \
                      "+v"(bsb[0]), "+v"(bsb[1]), "+v"(bsb[2]), "+v"(bsb[3]))

// R14 exp2 gate math (accums prescaled by -log2(e)):
//   c' = [c*Di*Dg + (1-Eg)*Df] * rcp(Df*Di*Dg);  h = (1-Ec) * rcp(Do*Dc).
#define GSTATE(AI, AF, AG, AO, CC, HH) do {                                   \
    const float Ei = __builtin_amdgcn_exp2f(AI);                              \
    const float Ef = __builtin_amdgcn_exp2f(AF);                              \
    const float Eg = __builtin_amdgcn_exp2f(AG);                              \
    const float Eo = __builtin_amdgcn_exp2f(AO);                              \
    const float Di = 1.0f + Ei, Df = 1.0f + Ef;                               \
    const float Dg = 1.0f + Eg, Do_ = 1.0f + Eo;                              \
    const float P  = Di * Dg;                                                 \
    const float t_ = (1.0f - Eg) * Df;                                        \
    const float u_ = __builtin_fmaf(CC, P, t_);                               \
    const float Rc = __builtin_amdgcn_rcpf(Df * P);                           \
    CC = u_ * Rc;                                                             \
    const float Ec = __builtin_amdgcn_exp2f(CC * N2L2E);                      \
    const float Dc = 1.0f + Ec;                                               \
    const float Rh = __builtin_amdgcn_rcpf(Do_ * Dc);                         \
    HH = (1.0f - Ec) * Rh;                                                    \
} while (0)

// One time step (this wave's half). PAR = step parity buffer (0/1).
//   4 MFMA K=32 -> 4 GSTATE -> cvt -> write own 8B -> barrier ->
//   read both halves (16B) -> B8 for next step.
#define STEP(XT, PAR) do {                                                    \
    const float xt = (XT);                                                    \
    v4f acc[4];                                                               \
    _Pragma("unroll")                                                         \
    for (int k = 0; k < 4; ++k) acc[k] = bsb[k] + wih[k] * xt;                \
    _Pragma("unroll")                                                         \
    for (int k = 0; k < 4; ++k) acc[k] = MF32(A8[k], B8, acc[k]);             \
    GSTATE(acc[0][0], acc[1][0], acc[2][0], acc[3][0], cs0, hv0);             \
    GSTATE(acc[0][1], acc[1][1], acc[2][1], acc[3][1], cs1, hv1);             \
    GSTATE(acc[0][2], acc[1][2], acc[2][2], acc[3][2], cs2, hv2);             \
    GSTATE(acc[0][3], acc[1][3], acc[2][3], acc[3][3], cs3, hv3);             \
    uint2 own;                                                                \
    own.x = __builtin_bit_cast(unsigned int,                                  \
                __builtin_amdgcn_cvt_pkrtz(hv0, hv1));                        \
    own.y = __builtin_bit_cast(unsigned int,                                  \
                __builtin_amdgcn_cvt_pkrtz(hv2, hv3));                        \
    hx[PAR][q][c][wv] = own;                                                  \
    __syncthreads();                                                          \
    B8 = mkB(*reinterpret_cast<const uint4*>(&hx[PAR][q][c][0]));             \
} while (0)

    // x staging: thread tid owns row r=tid>>3, cols colb..colb+3 of chunk.
    const int r    = tid >> 3;
    const int colb = (tid & 7) << 2;
    const float* xsrc = x + (size_t)(wbase + r) * T_LEN + colb;
    float4 xA = *reinterpret_cast<const float4*>(xsrc);

    for (int tc = 0; tc < T_LEN / 32; ++tc) {
        PINALL();
        *reinterpret_cast<float4*>(&xl[r][colb]) = xA;
        __syncthreads();                          // stage visible to both waves
        if (tc + 1 < T_LEN / 32)
            xA = *reinterpret_cast<const float4*>(xsrc + (tc + 1) * 32);
        const float* xc = &xl[c][0];
        #pragma unroll 4
        for (int tp = 0; tp < 16; ++tp) {         // pairs: explicit parity
            STEP(xc[2 * tp],     0);
            STEP(xc[2 * tp + 1], 1);
        }
    }
#undef STEP
#undef GSTATE
#undef PINALL

    // out[bb] = sum_u h[u]*W_fc[u] + b_fc. This wave: units 16wv+4q+m.
    const int u0 = 16 * wv + 4 * q;
    float val = hv0 * W_fc[u0]     + hv1 * W_fc[u0 + 1]
              + hv2 * W_fc[u0 + 2] + hv3 * W_fc[u0 + 3];
    val += __shfl_xor(val, 16);
    val += __shfl_xor(val, 32);
    if (q == 0) osum[wv][c] = val;
    __syncthreads();
    if (wv == 0 && q == 0 && bb < B)
        out[bb] = osum[0][c] + osum[1][c] + b_fc[0];
}

extern "C" void kernel_launch(void* const* d_in, const int* in_sizes, int n_in,
                              void* d_out, int out_size, void* d_ws, size_t ws_size,
                              hipStream_t stream) {
    const float* x    = (const float*)d_in[0];
    const float* W_ih = (const float*)d_in[1];
    const float* W_hh = (const float*)d_in[2];
    const float* b_ih = (const float*)d_in[3];
    const float* b_hh = (const float*)d_in[4];
    const float* W_fc = (const float*)d_in[5];
    const float* b_fc = (const float*)d_in[6];
    float* out = (float*)d_out;
    const int B = in_sizes[0] / T_LEN;        // 4096
    dim3 block(128);                          // 2 waves = 16 batch elements
    dim3 grid((B + 15) / 16);                 // 256 blocks -> 2 SIMDs/CU
    reslstm_kernel<<<grid, block, 0, stream>>>(x, W_ih, W_hh, b_ih, b_hh,
                                               W_fc, b_fc, out, B);
}

// Round 14
// 240.154 us; speedup vs baseline: 1.4998x; 1.0410x over previous
//
#include <hip/hip_runtime.h>

// ResLSTM: B=4096, T=512, H=32.
// R21 = R20 (two cooperating waves, MFMA recurrence) + exchange-stall cuts.
//   Block = 128 thr = 2 waves; wave w computes tiles {w,w+2,w+4,w+6}
//   (gate rows of units 16w..16w+15): 4 MFMA K=32 + 4 GSTATE per wave.
//   h exchange: parity-double-buffered LDS, ds_write b32x2 + barrier +
//   ds_read_b128 per step.
// R20 POST-MORTEM (197 us steady, 923 cy/step): VALU busy 554, MFMA 63,
//   IDLE 306 cy/step. __syncthreads drains vmcnt/expcnt each step
//   (re-serializes x prefetch) and is a hard sched barrier (no work can
//   fill the read-latency shadow). Bank conflicts only ~6 cy/step
//   (inherent b128 8-deep) -- not the problem.
// R21 cuts: (1) raw "s_waitcnt lgkmcnt(0); s_barrier" asm (memory clobber):
//   no vmcnt drain; register-only ops (next-step init fma, GSTATE tails)
//   CAN schedule across it into the stall shadow (rule-18 behavior used
//   for us). ds_write ordered by lgkmcnt; ds_read can't hoist (memory
//   clobber); MFMA held by dataflow. (2) x as one float4 LDS read per
//   4 steps -> xt in regs, hoistable inits. (3) split h-write: two b32s
//   issued as each GSTATE pair completes.
//   Race proof unchanged: read(t)[p] < own MFMA(t) < write(t+1)[1-p] <
//   barrier(t+1) < other's write(t+2)[p].
// History: R7 341. R11 297. R12 dot2 248. R14 230. R16 219 (VALU floor).
//   R18 K=16 305. R19 K=32 279 (MfmaUtil halved exactly -> layout right).
//   R20 2-wave split 197.
// Predict: 923 -> ~720-780 cy/step -> 155-170 us; VALUBusy(CU) ~36-40%;
//   MfmaUtil ~4.2%; absmax EXACTLY 0.0009765625. Failure <5% gain =>
//   exchange structurally irreducible -> near-floor evaluation.

static constexpr int T_LEN = 512;
static constexpr int H = 32;

typedef _Float16 h2   __attribute__((ext_vector_type(2)));
typedef __fp16   fp2  __attribute__((ext_vector_type(2)));   // cvt_pkrtz type
typedef _Float16 v8h  __attribute__((ext_vector_type(8)));
typedef float    v4f  __attribute__((ext_vector_type(4)));

// D = A(8 f16) x B(8 f16) + C(4 f32), 16x16x32 f16 MFMA (K=32).
__device__ __forceinline__ v4f MF32(v8h a, v8h b, v4f c) {
#if __has_builtin(__builtin_amdgcn_mfma_f32_16x16x32_f16)
    return __builtin_amdgcn_mfma_f32_16x16x32_f16(a, b, c, 0, 0, 0);
#else
    v4f d = c;
    asm("v_mfma_f32_16x16x32_f16 %0, %1, %2, %0" : "+v"(d) : "v"(a), "v"(b));
    return d;
#endif
}

__device__ __forceinline__ v8h mkB(uint4 w) {
    union { uint4 u; v8h v; } u;
    u.u = w; return u.v;
}

__global__ void
__attribute__((amdgpu_flat_work_group_size(128, 128), amdgpu_waves_per_eu(1, 1)))
reslstm_kernel(const float* __restrict__ x,
               const float* __restrict__ W_ih,
               const float* __restrict__ W_hh,
               const float* __restrict__ b_ih,
               const float* __restrict__ b_hh,
               const float* __restrict__ W_fc,
               const float* __restrict__ b_fc,
               float* __restrict__ out, int B)
{
    // x chunk: [batch-col][t], pad 36.
    __shared__ float xl[16][36];
    // h exchange, double-buffered by step parity: [buf][q][c][wave] 8B.
    __shared__ uint2 hx[2][4][16][2];
    __shared__ float osum[2][16];

    const int tid  = threadIdx.x;
    const int lane = tid & 63;
    const int wv   = tid >> 6;           // wave 0: units 0-15, wave 1: 16-31
    const int c    = lane & 15;          // batch col (0..15)
    const int q    = lane >> 4;          // row quad  (0..3)

    const int wbase = blockIdx.x << 4;   // 16 batches per block
    if (wbase >= B) return;              // block-uniform guard
    const int bb = wbase + c;

    constexpr float NL2E  = -1.4426950408889634f;   // -log2(e)
    constexpr float N2L2E = 2.0f * NL2E;

    // A fragments: tile t = 2k + wv (gate k of unit-half wv).
    //   A8[k][m]   = Whh_sc[16t + c][4q + m]      (k-half 0)
    //   A8[k][4+m] = Whh_sc[16t + c][16 + 4q + m] (k-half 1)
    // Prescale: g gate (k==2) by 2*-log2(e), else -log2(e).
    v8h A8[4];
    v4f wih[4], bsb[4];
    #pragma unroll
    for (int k = 0; k < 4; ++k) {
        const int   t  = 2 * k + wv;
        const float sc = (k == 2) ? N2L2E : NL2E;
        const float4 w1 = *reinterpret_cast<const float4*>(
            W_hh + (16 * t + c) * H + 4 * q);
        const float4 w2 = *reinterpret_cast<const float4*>(
            W_hh + (16 * t + c) * H + 16 + 4 * q);
        A8[k][0] = (_Float16)(w1.x * sc); A8[k][1] = (_Float16)(w1.y * sc);
        A8[k][2] = (_Float16)(w1.z * sc); A8[k][3] = (_Float16)(w1.w * sc);
        A8[k][4] = (_Float16)(w2.x * sc); A8[k][5] = (_Float16)(w2.y * sc);
        A8[k][6] = (_Float16)(w2.z * sc); A8[k][7] = (_Float16)(w2.w * sc);
        const int r0 = 16 * t + 4 * q;
        const float4 wi = *reinterpret_cast<const float4*>(W_ih + r0);
        const float4 bi = *reinterpret_cast<const float4*>(b_ih + r0);
        const float4 bh = *reinterpret_cast<const float4*>(b_hh + r0);
        wih[k][0] = wi.x * sc; wih[k][1] = wi.y * sc;
        wih[k][2] = wi.z * sc; wih[k][3] = wi.w * sc;
        bsb[k][0] = (bi.x + bh.x) * sc; bsb[k][1] = (bi.y + bh.y) * sc;
        bsb[k][2] = (bi.z + bh.z) * sc; bsb[k][3] = (bi.w + bh.w) * sc;
    }

    // State: this wave's 4 units (16wv + 4q + m).
    float cs0 = 0.f, cs1 = 0.f, cs2 = 0.f, cs3 = 0.f;
    float hv0 = 0.f, hv1 = 0.f, hv2 = 0.f, hv3 = 0.f;
    v8h B8 = mkB(uint4{0u, 0u, 0u, 0u});          // h(0) = 0

// Light pins once per chunk (R6 lesson: asm outputs can't be rematerialized
// from memory -> weights stay VGPR-resident; R13: placement neutral).
#define PINALL()                                                              \
    asm volatile("" : "+v"(A8[0]), "+v"(A8[1]), "+v"(A8[2]), "+v"(A8[3]));    \
    asm volatile("" : "+v"(wih[0]), "+v"(wih[1]), "+v"(wih[2]), "+v"(wih[3]), \
                      "+v"(bsb[0]), "+v"(bsb[1]), "+v"(bsb[2]), "+v"(bsb[3]))

// R14 exp2 gate math (accums prescaled by -log2(e)):
//   c' = [c*Di*Dg + (1-Eg)*Df] * rcp(Df*Di*Dg);  h = (1-Ec) * rcp(Do*Dc).
#define GSTATE(AI, AF, AG, AO, CC, HH) do {                                   \
    const float Ei = __builtin_amdgcn_exp2f(AI);                              \
    const float Ef = __builtin_amdgcn_exp2f(AF);                              \
    const float Eg = __builtin_amdgcn_exp2f(AG);                              \
    const float Eo = __builtin_amdgcn_exp2f(AO);                              \
    const float Di = 1.0f + Ei, Df = 1.0f + Ef;                               \
    const float Dg = 1.0f + Eg, Do_ = 1.0f + Eo;                              \
    const float P  = Di * Dg;                                                 \
    const float t_ = (1.0f - Eg) * Df;                                        \
    const float u_ = __builtin_fmaf(CC, P, t_);                               \
    const float Rc = __builtin_amdgcn_rcpf(Df * P);                           \
    CC = u_ * Rc;                                                             \
    const float Ec = __builtin_amdgcn_exp2f(CC * N2L2E);                      \
    const float Dc = 1.0f + Ec;                                               \
    const float Rh = __builtin_amdgcn_rcpf(Do_ * Dc);                         \
    HH = (1.0f - Ec) * Rh;                                                    \
} while (0)

// One time step (this wave's half). PAR = step parity buffer (0/1).
// 4 MFMA -> 4 GSTATE (paired, each pair's h written as b32 ASAP) ->
// raw lgkmcnt+barrier -> b128 read of both halves -> B8 for next step.
#define STEP(XT, PAR) do {                                                    \
    const float xt = (XT);                                                    \
    v4f acc[4];                                                               \
    _Pragma("unroll")                                                         \
    for (int k = 0; k < 4; ++k) acc[k] = bsb[k] + wih[k] * xt;                \
    _Pragma("unroll")                                                         \
    for (int k = 0; k < 4; ++k) acc[k] = MF32(A8[k], B8, acc[k]);             \
    unsigned int* slot =                                                      \
        reinterpret_cast<unsigned int*>(&hx[PAR][q][c][wv]);                  \
    GSTATE(acc[0][0], acc[1][0], acc[2][0], acc[3][0], cs0, hv0);             \
    GSTATE(acc[0][1], acc[1][1], acc[2][1], acc[3][1], cs1, hv1);             \
    slot[0] = __builtin_bit_cast(unsigned int,                                \
                  __builtin_amdgcn_cvt_pkrtz(hv0, hv1));                      \
    GSTATE(acc[0][2], acc[1][2], acc[2][2], acc[3][2], cs2, hv2);             \
    GSTATE(acc[0][3], acc[1][3], acc[2][3], acc[3][3], cs3, hv3);             \
    slot[1] = __builtin_bit_cast(unsigned int,                                \
                  __builtin_amdgcn_cvt_pkrtz(hv2, hv3));                      \
    asm volatile("s_waitcnt lgkmcnt(0)\n\ts_barrier" ::: "memory");           \
    B8 = mkB(*reinterpret_cast<const uint4*>(&hx[PAR][q][c][0]));             \
} while (0)

    // x staging: thread tid owns row r=tid>>3, cols colb..colb+3 of chunk.
    const int r    = tid >> 3;
    const int colb = (tid & 7) << 2;
    const float* xsrc = x + (size_t)(wbase + r) * T_LEN + colb;
    float4 xA = *reinterpret_cast<const float4*>(xsrc);

    for (int tc = 0; tc < T_LEN / 32; ++tc) {
        PINALL();
        *reinterpret_cast<float4*>(&xl[r][colb]) = xA;
        __syncthreads();                  // stage visible to both waves
        if (tc + 1 < T_LEN / 32)
            xA = *reinterpret_cast<const float4*>(xsrc + (tc + 1) * 32);
        const float4* xq4c = reinterpret_cast<const float4*>(&xl[c][0]);
        #pragma unroll 2
        for (int t4 = 0; t4 < 8; ++t4) {
            const float4 xv = xq4c[t4];   // 4 steps of x in regs
            STEP(xv.x, 0);
            STEP(xv.y, 1);
            STEP(xv.z, 0);
            STEP(xv.w, 1);
        }
    }
#undef STEP
#undef GSTATE
#undef PINALL

    // out[bb] = sum_u h[u]*W_fc[u] + b_fc. This wave: units 16wv+4q+m.
    const int u0 = 16 * wv + 4 * q;
    float val = hv0 * W_fc[u0]     + hv1 * W_fc[u0 + 1]
              + hv2 * W_fc[u0 + 2] + hv3 * W_fc[u0 + 3];
    val += __shfl_xor(val, 16);
    val += __shfl_xor(val, 32);
    if (q == 0) osum[wv][c] = val;
    __syncthreads();
    if (wv == 0 && q == 0 && bb < B)
        out[bb] = osum[0][c] + osum[1][c] + b_fc[0];
}

extern "C" void kernel_launch(void* const* d_in, const int* in_sizes, int n_in,
                              void* d_out, int out_size, void* d_ws, size_t ws_size,
                              hipStream_t stream) {
    const float* x    = (const float*)d_in[0];
    const float* W_ih = (const float*)d_in[1];
    const float* W_hh = (const float*)d_in[2];
    const float* b_ih = (const float*)d_in[3];
    const float* b_hh = (const float*)d_in[4];
    const float* W_fc = (const float*)d_in[5];
    const float* b_fc = (const float*)d_in[6];
    float* out = (float*)d_out;
    const int B = in_sizes[0] / T_LEN;        // 4096
    dim3 block(128);                          // 2 waves = 16 batch elements
    dim3 grid((B + 15) / 16);                 // 256 blocks -> 2 SIMDs/CU
    reslstm_kernel<<<grid, block, 0, stream>>>(x, W_ih, W_hh, b_ih, b_hh,
                                               W_fc, b_fc, out, B);
}